// Round 4
// baseline (504.755 us; speedup 1.0000x reference)
//
#include <hip/hip_runtime.h>
#include <stdint.h>

#define BSZ 64
#define SEQ 197
#define EMB 768
#define NH  12
#define HD  64
#define M_TOK (BSZ*SEQ)      // 12608 token rows
#define SHD (SEQ*HD)         // 12608 elements per (b,h) head matrix

using bf16x8 = __attribute__((ext_vector_type(8))) short;
using f32x4  = __attribute__((ext_vector_type(4))) float;

__device__ __forceinline__ float bflo(uint32_t u) { return __uint_as_float(u << 16); }
__device__ __forceinline__ float bfhi(uint32_t u) { return __uint_as_float(u & 0xffff0000u); }
__device__ __forceinline__ uint16_t f2bf(float f) {
    uint32_t u = __float_as_uint(f);
    u += 0x7fffu + ((u >> 16) & 1u);   // RNE
    return (uint16_t)(u >> 16);
}

// ---------------------------------------------------------------- convert
// Inputs are fp32 (established round 3: NaN signature of fp32-as-bf16 misread
// disappeared once converted). Always fp32 -> bf16.
struct CvtJob { const float* src; uint16_t* dst; int n8; };   // n8 = elems/8
struct CvtJobs { CvtJob j[9]; };

__global__ __launch_bounds__(256) void convert_kernel(CvtJobs jobs)
{
    int idx = blockIdx.x * 256 + threadIdx.x;   // 8-element chunk index
    #pragma unroll
    for (int r = 0; r < 9; ++r) {
        const int n8 = jobs.j[r].n8;
        if (idx < n8) {
            const uint4* s4 = (const uint4*)(jobs.j[r].src + (size_t)idx * 8);
            uint4 a = s4[0], b = s4[1];
            uint4 w;
            w.x = (uint32_t)f2bf(__uint_as_float(a.x)) | ((uint32_t)f2bf(__uint_as_float(a.y)) << 16);
            w.y = (uint32_t)f2bf(__uint_as_float(a.z)) | ((uint32_t)f2bf(__uint_as_float(a.w)) << 16);
            w.z = (uint32_t)f2bf(__uint_as_float(b.x)) | ((uint32_t)f2bf(__uint_as_float(b.y)) << 16);
            w.w = (uint32_t)f2bf(__uint_as_float(b.z)) | ((uint32_t)f2bf(__uint_as_float(b.w)) << 16);
            *(uint4*)(jobs.j[r].dst + (size_t)idx * 8) = w;
            return;
        }
        idx -= n8;
    }
}

// ---------------------------------------------------------------- GEMM
struct GemmPtrs {
    const uint16_t* W[3];
    const uint16_t* b[3];
    void*           out[3];
};

// C[m][n] = sum_k A[m][k] * W[n][k] + bias[n]  (NT, bf16 in, fp32 acc)
// outf32: 0 -> bf16 C, 1 -> fp32 C (final output is fp32 per round-3 evidence)
__global__ __launch_bounds__(256) void gemm_bias_nt(const uint16_t* __restrict__ A,
                                                    GemmPtrs p, int M, int outf32)
{
    __shared__ __align__(16) uint16_t sA[128 * 32];
    __shared__ __align__(16) uint16_t sB[128 * 32];

    const int z = blockIdx.z;
    const uint16_t* __restrict__ W    = p.W[z];
    const uint16_t* __restrict__ bias = p.b[z];

    const int m0   = blockIdx.x * 128;
    const int n0   = blockIdx.y * 128;
    const int tid  = threadIdx.x;
    const int lane = tid & 63;
    const int wave = tid >> 6;
    const int wr = wave >> 1, wc = wave & 1;
    const int l15 = lane & 15;
    const int kq  = lane >> 4;        // 0..3 -> k offset kq*8

    const int c0 = tid, c1 = tid + 256;
    const int row0 = c0 >> 2, kc0 = c0 & 3;
    const int row1 = c1 >> 2, kc1 = c1 & 3;
    int ga0 = m0 + row0; if (ga0 >= M) ga0 = M - 1;
    int ga1 = m0 + row1; if (ga1 >= M) ga1 = M - 1;
    const uint16_t* a0p = A + (size_t)ga0 * EMB + kc0 * 8;
    const uint16_t* a1p = A + (size_t)ga1 * EMB + kc1 * 8;
    const uint16_t* b0p = W + (size_t)(n0 + row0) * EMB + kc0 * 8;
    const uint16_t* b1p = W + (size_t)(n0 + row1) * EMB + kc1 * 8;

    f32x4 acc[4][4] = {};

    for (int k0 = 0; k0 < EMB; k0 += 32) {
        uint4 av0 = *(const uint4*)(a0p + k0);
        uint4 av1 = *(const uint4*)(a1p + k0);
        uint4 bv0 = *(const uint4*)(b0p + k0);
        uint4 bv1 = *(const uint4*)(b1p + k0);
        *(uint4*)(sA + c0 * 8) = av0;
        *(uint4*)(sA + c1 * 8) = av1;
        *(uint4*)(sB + c0 * 8) = bv0;
        *(uint4*)(sB + c1 * 8) = bv1;
        __syncthreads();

        bf16x8 af[4], bfr[4];
        #pragma unroll
        for (int i = 0; i < 4; ++i)
            af[i] = *(const bf16x8*)(sA + (64 * wr + 16 * i + l15) * 32 + kq * 8);
        #pragma unroll
        for (int j = 0; j < 4; ++j)
            bfr[j] = *(const bf16x8*)(sB + (64 * wc + 16 * j + l15) * 32 + kq * 8);

        #pragma unroll
        for (int i = 0; i < 4; ++i)
            #pragma unroll
            for (int j = 0; j < 4; ++j)
                acc[i][j] = __builtin_amdgcn_mfma_f32_16x16x32_bf16(af[i], bfr[j], acc[i][j], 0, 0, 0);

        __syncthreads();
    }

    // C/D layout: col = lane&15, row = (lane>>4)*4 + reg
    #pragma unroll
    for (int j = 0; j < 4; ++j) {
        int n = n0 + 64 * wc + 16 * j + l15;
        float bv = bflo((uint32_t)bias[n]);
        #pragma unroll
        for (int i = 0; i < 4; ++i) {
            #pragma unroll
            for (int r = 0; r < 4; ++r) {
                int m = m0 + 64 * wr + 16 * i + kq * 4 + r;
                if (m < M) {
                    float v = acc[i][j][r] + bv;
                    if (outf32) ((float*)p.out[z])[(size_t)m * EMB + n] = v;
                    else        ((uint16_t*)p.out[z])[(size_t)m * EMB + n] = f2bf(v);
                }
            }
        }
    }
}

// ---------------------------------------------------------------- attention
// One workgroup per (b,h); K,V in LDS; one thread per query row; fp32 acc.
// softmax-then-/sqrt(E) quirk folded into 1/(l*sqrt(768)).
__global__ __launch_bounds__(256) void attn_kernel(const uint16_t* __restrict__ Qg,
                                                   const uint16_t* __restrict__ Kg,
                                                   const uint16_t* __restrict__ Vg,
                                                   uint16_t* __restrict__ Og)
{
    __shared__ uint4 sK[SHD / 8];   // 25216 B
    __shared__ uint4 sV[SHD / 8];

    const int bh = blockIdx.x;
    const size_t base = (size_t)bh * SHD;
    const int tid = threadIdx.x;

    const uint4* kg4 = (const uint4*)(Kg + base);
    const uint4* vg4 = (const uint4*)(Vg + base);
    for (int c = tid; c < SHD / 8; c += 256) {
        sK[c] = kg4[c];
        sV[c] = vg4[c];
    }
    __syncthreads();

    if (tid < SEQ) {
        float qf[HD];
        const uint4* qg4 = (const uint4*)(Qg + base + tid * HD);
        #pragma unroll
        for (int t = 0; t < 8; ++t) {
            uint4 q = qg4[t];
            qf[8*t+0] = bflo(q.x); qf[8*t+1] = bfhi(q.x);
            qf[8*t+2] = bflo(q.y); qf[8*t+3] = bfhi(q.y);
            qf[8*t+4] = bflo(q.z); qf[8*t+5] = bfhi(q.z);
            qf[8*t+6] = bflo(q.w); qf[8*t+7] = bfhi(q.w);
        }
        float o[HD];
        #pragma unroll
        for (int d = 0; d < HD; ++d) o[d] = 0.f;
        float l = 0.f;

        for (int j = 0; j < SEQ; ++j) {
            float s = 0.f;
            #pragma unroll
            for (int t = 0; t < 8; ++t) {
                uint4 kk = sK[j * 8 + t];
                s += qf[8*t+0] * bflo(kk.x) + qf[8*t+1] * bfhi(kk.x)
                   + qf[8*t+2] * bflo(kk.y) + qf[8*t+3] * bfhi(kk.y)
                   + qf[8*t+4] * bflo(kk.z) + qf[8*t+5] * bfhi(kk.z)
                   + qf[8*t+6] * bflo(kk.w) + qf[8*t+7] * bfhi(kk.w);
            }
            s = fminf(s, 80.f);       // never fires on correct data
            float pw = __expf(s);
            l += pw;
            #pragma unroll
            for (int t = 0; t < 8; ++t) {
                uint4 vv = sV[j * 8 + t];
                o[8*t+0] += pw * bflo(vv.x); o[8*t+1] += pw * bfhi(vv.x);
                o[8*t+2] += pw * bflo(vv.y); o[8*t+3] += pw * bfhi(vv.y);
                o[8*t+4] += pw * bflo(vv.z); o[8*t+5] += pw * bfhi(vv.z);
                o[8*t+6] += pw * bflo(vv.w); o[8*t+7] += pw * bfhi(vv.w);
            }
        }

        const float scale = 1.f / (l * 27.712812921102035f);  // l * sqrt(768)
        uint4* orow = (uint4*)(Og + base + tid * HD);
        #pragma unroll
        for (int t = 0; t < 8; ++t) {
            uint4 w;
            w.x = (uint32_t)f2bf(o[8*t+0] * scale) | ((uint32_t)f2bf(o[8*t+1] * scale) << 16);
            w.y = (uint32_t)f2bf(o[8*t+2] * scale) | ((uint32_t)f2bf(o[8*t+3] * scale) << 16);
            w.z = (uint32_t)f2bf(o[8*t+4] * scale) | ((uint32_t)f2bf(o[8*t+5] * scale) << 16);
            w.w = (uint32_t)f2bf(o[8*t+6] * scale) | ((uint32_t)f2bf(o[8*t+7] * scale) << 16);
            orow[t] = w;
        }
    }
}

// ---------------------------------------------------------------- launch
extern "C" void kernel_launch(void* const* d_in, const int* in_sizes, int n_in,
                              void* d_out, int out_size, void* d_ws, size_t ws_size,
                              hipStream_t stream)
{
    const size_t NX = (size_t)M_TOK * EMB;   // 9,682,944
    const size_t NW = (size_t)EMB * EMB;     //   589,824
    const size_t NB = EMB;

    uint16_t* xbf = (uint16_t*)d_ws;
    uint16_t* Wbf[4]; uint16_t* bbf[4];
    uint16_t* cur = xbf + NX;
    for (int i = 0; i < 4; ++i) { Wbf[i] = cur; cur += NW; }
    for (int i = 0; i < 4; ++i) { bbf[i] = cur; cur += NB; }
    uint16_t* Qw = cur;
    uint16_t* Kw = Qw + NX;
    uint16_t* Vw = Kw + NX;

    const size_t need_primary  = 2 * (NX + 4 * NW + 4 * NB + 3 * NX);  // ~82 MB
    const size_t need_fallback = need_primary - 2 * NX;                 // ~63 MB
    if (ws_size < need_fallback) return;               // sentinel: absmax ~0.0845
    if (ws_size < need_primary) Vw = (uint16_t*)d_out; // V bf16 scratch in d_out
                                                       // (consumed by attn before
                                                       // proj overwrites with fp32)

    CvtJobs jobs;
    jobs.j[0] = { (const float*)d_in[0], xbf,    (int)(NX / 8) };
    jobs.j[1] = { (const float*)d_in[1], Wbf[0], (int)(NW / 8) };
    jobs.j[2] = { (const float*)d_in[3], Wbf[1], (int)(NW / 8) };
    jobs.j[3] = { (const float*)d_in[5], Wbf[2], (int)(NW / 8) };
    jobs.j[4] = { (const float*)d_in[7], Wbf[3], (int)(NW / 8) };
    jobs.j[5] = { (const float*)d_in[2], bbf[0], (int)(NB / 8) };
    jobs.j[6] = { (const float*)d_in[4], bbf[1], (int)(NB / 8) };
    jobs.j[7] = { (const float*)d_in[6], bbf[2], (int)(NB / 8) };
    jobs.j[8] = { (const float*)d_in[8], bbf[3], (int)(NB / 8) };
    const int total8 = (int)((NX + 4 * NW + 4 * NB) / 8);
    convert_kernel<<<(total8 + 255) / 256, 256, 0, stream>>>(jobs);

    GemmPtrs qkv;
    qkv.W[0] = Wbf[0]; qkv.W[1] = Wbf[1]; qkv.W[2] = Wbf[2];
    qkv.b[0] = bbf[0]; qkv.b[1] = bbf[1]; qkv.b[2] = bbf[2];
    qkv.out[0] = Qw; qkv.out[1] = Kw; qkv.out[2] = Vw;
    dim3 g1((M_TOK + 127) / 128, EMB / 128, 3);
    gemm_bias_nt<<<g1, 256, 0, stream>>>(xbf, qkv, M_TOK, 0);

    // attn output aliases Qw (disjoint per-(b,h) slices; each row is read by
    // its own thread before that same thread writes it)
    attn_kernel<<<dim3(BSZ * NH), 256, 0, stream>>>(Qw, Kw, Vw, Qw);

    GemmPtrs pr;
    pr.W[0] = pr.W[1] = pr.W[2] = Wbf[3];
    pr.b[0] = pr.b[1] = pr.b[2] = bbf[3];
    pr.out[0] = pr.out[1] = pr.out[2] = d_out;         // fp32 final output
    dim3 g2((M_TOK + 127) / 128, EMB / 128, 1);
    gemm_bias_nt<<<g2, 256, 0, stream>>>(Qw, pr, M_TOK, 1);
}

// Round 5
// 274.532 us; speedup vs baseline: 1.8386x; 1.8386x over previous
//
#include <hip/hip_runtime.h>
#include <stdint.h>

#define BSZ 64
#define SEQ 197
#define EMB 768
#define NH  12
#define HD  64
#define M_TOK (BSZ*SEQ)      // 12608 token rows
#define SHD (SEQ*HD)         // 12608 elements per (b,h) head matrix

using bf16x8 = __attribute__((ext_vector_type(8))) short;
using f32x4  = __attribute__((ext_vector_type(4))) float;

__device__ __forceinline__ float bflo(uint32_t u) { return __uint_as_float(u << 16); }
__device__ __forceinline__ uint16_t f2bf(float f) {
    uint32_t u = __float_as_uint(f);
    u += 0x7fffu + ((u >> 16) & 1u);   // RNE
    return (uint16_t)(u >> 16);
}

// ---------------------------------------------------------------- convert
// Inputs fp32 (round-3 evidence). fp32 -> bf16 into ws.
struct CvtJob { const float* src; uint16_t* dst; int n8; };
struct CvtJobs { CvtJob j[9]; };

__global__ __launch_bounds__(256) void convert_kernel(CvtJobs jobs)
{
    int idx = blockIdx.x * 256 + threadIdx.x;
    #pragma unroll
    for (int r = 0; r < 9; ++r) {
        const int n8 = jobs.j[r].n8;
        if (idx < n8) {
            const uint4* s4 = (const uint4*)(jobs.j[r].src + (size_t)idx * 8);
            uint4 a = s4[0], b = s4[1];
            uint4 w;
            w.x = (uint32_t)f2bf(__uint_as_float(a.x)) | ((uint32_t)f2bf(__uint_as_float(a.y)) << 16);
            w.y = (uint32_t)f2bf(__uint_as_float(a.z)) | ((uint32_t)f2bf(__uint_as_float(a.w)) << 16);
            w.z = (uint32_t)f2bf(__uint_as_float(b.x)) | ((uint32_t)f2bf(__uint_as_float(b.y)) << 16);
            w.w = (uint32_t)f2bf(__uint_as_float(b.z)) | ((uint32_t)f2bf(__uint_as_float(b.w)) << 16);
            *(uint4*)(jobs.j[r].dst + (size_t)idx * 8) = w;
            return;
        }
        idx -= n8;
    }
}

// ---------------------------------------------------------------- GEMM
struct GemmPtrs {
    const uint16_t* W[3];
    const uint16_t* b[3];
    void*           out[3];
};

// C[m][n] = sum_k A[m][k]*W[n][k] + bias[n]  (NT, bf16 in, fp32 acc)
// global_load_lds staging (m97 pattern; exonerated — round-1 NaN was input dtype)
__global__ __launch_bounds__(256) void gemm_bias_nt(const uint16_t* __restrict__ A,
                                                    GemmPtrs p, int M, int outf32)
{
    __shared__ __align__(16) uint16_t sA[128 * 32];
    __shared__ __align__(16) uint16_t sB[128 * 32];

    const int z = blockIdx.z;
    const uint16_t* __restrict__ W    = p.W[z];
    const uint16_t* __restrict__ bias = p.b[z];

    const int m0   = blockIdx.x * 128;
    const int n0   = blockIdx.y * 128;
    const int tid  = threadIdx.x;
    const int lane = tid & 63;
    const int wave = tid >> 6;
    const int wr = wave >> 1, wc = wave & 1;
    const int l15 = lane & 15;
    const int kq  = lane >> 4;

    const int c0 = tid, c1 = tid + 256;
    const int row0 = c0 >> 2, kc0 = c0 & 3;
    const int row1 = c1 >> 2, kc1 = c1 & 3;
    int ga0 = m0 + row0; if (ga0 >= M) ga0 = M - 1;
    int ga1 = m0 + row1; if (ga1 >= M) ga1 = M - 1;
    const uint16_t* a0p = A + (size_t)ga0 * EMB + kc0 * 8;
    const uint16_t* a1p = A + (size_t)ga1 * EMB + kc1 * 8;
    const uint16_t* b0p = W + (size_t)(n0 + row0) * EMB + kc0 * 8;
    const uint16_t* b1p = W + (size_t)(n0 + row1) * EMB + kc1 * 8;

    f32x4 acc[4][4] = {};

    for (int k0 = 0; k0 < EMB; k0 += 32) {
        __builtin_amdgcn_global_load_lds(
            (const __attribute__((address_space(1))) void*)(a0p + k0),
            (__attribute__((address_space(3))) void*)(sA + c0 * 8), 16, 0, 0);
        __builtin_amdgcn_global_load_lds(
            (const __attribute__((address_space(1))) void*)(a1p + k0),
            (__attribute__((address_space(3))) void*)(sA + c1 * 8), 16, 0, 0);
        __builtin_amdgcn_global_load_lds(
            (const __attribute__((address_space(1))) void*)(b0p + k0),
            (__attribute__((address_space(3))) void*)(sB + c0 * 8), 16, 0, 0);
        __builtin_amdgcn_global_load_lds(
            (const __attribute__((address_space(1))) void*)(b1p + k0),
            (__attribute__((address_space(3))) void*)(sB + c1 * 8), 16, 0, 0);
        asm volatile("s_waitcnt vmcnt(0)" ::: "memory");
        __syncthreads();

        bf16x8 af[4], bfr[4];
        #pragma unroll
        for (int i = 0; i < 4; ++i)
            af[i] = *(const bf16x8*)(sA + (64 * wr + 16 * i + l15) * 32 + kq * 8);
        #pragma unroll
        for (int j = 0; j < 4; ++j)
            bfr[j] = *(const bf16x8*)(sB + (64 * wc + 16 * j + l15) * 32 + kq * 8);

        #pragma unroll
        for (int i = 0; i < 4; ++i)
            #pragma unroll
            for (int j = 0; j < 4; ++j)
                acc[i][j] = __builtin_amdgcn_mfma_f32_16x16x32_bf16(af[i], bfr[j], acc[i][j], 0, 0, 0);

        __syncthreads();
    }

    // C/D: col = lane&15, row = (lane>>4)*4 + reg
    #pragma unroll
    for (int j = 0; j < 4; ++j) {
        int n = n0 + 64 * wc + 16 * j + l15;
        float bv = bflo((uint32_t)bias[n]);
        #pragma unroll
        for (int i = 0; i < 4; ++i) {
            #pragma unroll
            for (int r = 0; r < 4; ++r) {
                int m = m0 + 64 * wr + 16 * i + kq * 4 + r;
                if (m < M) {
                    float v = acc[i][j][r] + bv;
                    if (outf32) ((float*)p.out[z])[(size_t)m * EMB + n] = v;
                    else        ((uint16_t*)p.out[z])[(size_t)m * EMB + n] = f2bf(v);
                }
            }
        }
    }
}

// ---------------------------------------------------------------- attention (MFMA)
// One block per (b,h); 4 waves; wave w owns query rows 64w..64w+63 (4 m-tiles).
// Keys processed in 4 chunks of 64 (padded 256; phantom keys -> P=0, Vt=0).
// QK^T: NT MFMA, Q frags in regs, K frags direct from global.
// P: C-layout -> exp -> bf16 -> wave-private LDS -> A-layout frags (m120 pattern).
// PV: B operand from d-major V^T staged in LDS. Row sums l via ones-B MFMA.
// softmax-then-/sqrt(E) quirk folded into 1/(l*sqrt(768)).
#define RV 264   // sVt row stride (keys), 528B = 4-bank offset/row, 16B aligned
#define RP 72    // sP row stride, 144B = 4-bank offset/row, 16B aligned
__global__ __launch_bounds__(256) void attn_kernel(const uint16_t* __restrict__ Qg,
                                                   const uint16_t* __restrict__ Kg,
                                                   const uint16_t* __restrict__ Vg,
                                                   uint16_t* __restrict__ Og)
{
    __shared__ __align__(16) uint16_t sVt[HD * RV];        // 33792 B, d-major V^T
    __shared__ __align__(16) uint16_t sP[4][64 * RP];      // 36864 B, per-wave P

    const int bh  = blockIdx.x;
    const size_t base = (size_t)bh * SHD;
    const int tid  = threadIdx.x;
    const int lane = tid & 63;
    const int w    = tid >> 6;
    const int l15  = lane & 15;
    const int kq   = lane >> 4;
    uint16_t* sPw = sP[w];

    // ---- zero phantom-key columns of sVt (keys 197..263) ----
    {
        int r = tid >> 2, t4 = tid & 3;
        for (int c = SEQ + t4; c < RV; c += 4) sVt[r * RV + c] = 0;
    }
    // ---- stage V^T: V[key][d] -> sVt[d][key] ----
    for (int idx = tid; idx < SHD / 8; idx += 256) {
        int key = idx >> 3, dc = idx & 7;
        uint4 v = ((const uint4*)(Vg + base))[idx];
        uint16_t e[8];
        *(uint4*)e = v;
        #pragma unroll
        for (int j = 0; j < 8; ++j) sVt[(dc * 8 + j) * RV + key] = e[j];
    }

    // ---- Q fragments (held in regs whole kernel); rows >=197 clamped ----
    bf16x8 aq[4][2];
    #pragma unroll
    for (int mi = 0; mi < 4; ++mi) {
        int m = 64 * w + 16 * mi + l15; if (m >= SEQ) m = SEQ - 1;
        const uint16_t* qp = Qg + base + (size_t)m * HD + kq * 8;
        aq[mi][0] = *(const bf16x8*)(qp);
        aq[mi][1] = *(const bf16x8*)(qp + 32);
    }

    // ones B fragment (bf16 1.0)
    bf16x8 ones;
    #pragma unroll
    for (int j = 0; j < 8; ++j) ones[j] = (short)0x3F80;

    f32x4 oacc[4][4] = {};
    f32x4 lacc[4]    = {};

    __syncthreads();   // sVt ready

    for (int c = 0; c < 4; ++c) {
        // ---- QK^T ----
        bf16x8 bk[4][2];
        #pragma unroll
        for (int ni = 0; ni < 4; ++ni) {
            int key = 64 * c + 16 * ni + l15; if (key >= SEQ) key = SEQ - 1;
            const uint16_t* kp = Kg + base + (size_t)key * HD + kq * 8;
            bk[ni][0] = *(const bf16x8*)(kp);
            bk[ni][1] = *(const bf16x8*)(kp + 32);
        }
        #pragma unroll
        for (int mi = 0; mi < 4; ++mi) {
            #pragma unroll
            for (int ni = 0; ni < 4; ++ni) {
                f32x4 s = {};
                s = __builtin_amdgcn_mfma_f32_16x16x32_bf16(aq[mi][0], bk[ni][0], s, 0, 0, 0);
                s = __builtin_amdgcn_mfma_f32_16x16x32_bf16(aq[mi][1], bk[ni][1], s, 0, 0, 0);
                // exp + store P to wave-private LDS (C-layout -> row-major)
                int col = 16 * ni + l15;
                int key = 64 * c + col;
                #pragma unroll
                for (int r = 0; r < 4; ++r) {
                    float pv = (key < SEQ) ? __expf(fminf(s[r], 80.f)) : 0.f;
                    sPw[(16 * mi + kq * 4 + r) * RP + col] = f2bf(pv);
                }
            }
        }
        // wave-private LDS: no barrier needed (compiler orders via lgkmcnt)

        // ---- PV + l ----
        bf16x8 bv[2][4];
        #pragma unroll
        for (int kk = 0; kk < 2; ++kk)
            #pragma unroll
            for (int ni = 0; ni < 4; ++ni)
                bv[kk][ni] = *(const bf16x8*)(sVt + (16 * ni + l15) * RV + c * 64 + kk * 32 + kq * 8);

        #pragma unroll
        for (int mi = 0; mi < 4; ++mi) {
            #pragma unroll
            for (int kk = 0; kk < 2; ++kk) {
                bf16x8 ap = *(const bf16x8*)(sPw + (16 * mi + l15) * RP + kk * 32 + kq * 8);
                lacc[mi] = __builtin_amdgcn_mfma_f32_16x16x32_bf16(ap, ones, lacc[mi], 0, 0, 0);
                #pragma unroll
                for (int ni = 0; ni < 4; ++ni)
                    oacc[mi][ni] = __builtin_amdgcn_mfma_f32_16x16x32_bf16(ap, bv[kk][ni], oacc[mi][ni], 0, 0, 0);
            }
        }
    }

    // ---- epilogue: scale by 1/(l*sqrt(768)), store bf16 ----
    #pragma unroll
    for (int mi = 0; mi < 4; ++mi) {
        #pragma unroll
        for (int r = 0; r < 4; ++r) {
            int m = 64 * w + 16 * mi + kq * 4 + r;
            if (m < SEQ) {
                float scale = 1.f / (lacc[mi][r] * 27.712812921102035f);
                #pragma unroll
                for (int ni = 0; ni < 4; ++ni)
                    Og[base + (size_t)m * HD + 16 * ni + l15] = f2bf(oacc[mi][ni][r] * scale);
            }
        }
    }
}

// ---------------------------------------------------------------- launch
extern "C" void kernel_launch(void* const* d_in, const int* in_sizes, int n_in,
                              void* d_out, int out_size, void* d_ws, size_t ws_size,
                              hipStream_t stream)
{
    const size_t NX = (size_t)M_TOK * EMB;
    const size_t NW = (size_t)EMB * EMB;
    const size_t NB = EMB;

    uint16_t* xbf = (uint16_t*)d_ws;
    uint16_t* Wbf[4]; uint16_t* bbf[4];
    uint16_t* cur = xbf + NX;
    for (int i = 0; i < 4; ++i) { Wbf[i] = cur; cur += NW; }
    for (int i = 0; i < 4; ++i) { bbf[i] = cur; cur += NB; }
    uint16_t* Qw = cur;
    uint16_t* Kw = Qw + NX;
    uint16_t* Vw = Kw + NX;

    const size_t need_primary  = 2 * (NX + 4 * NW + 4 * NB + 3 * NX);
    const size_t need_fallback = need_primary - 2 * NX;
    if (ws_size < need_fallback) return;
    if (ws_size < need_primary) Vw = (uint16_t*)d_out;  // V scratch in d_out

    CvtJobs jobs;
    jobs.j[0] = { (const float*)d_in[0], xbf,    (int)(NX / 8) };
    jobs.j[1] = { (const float*)d_in[1], Wbf[0], (int)(NW / 8) };
    jobs.j[2] = { (const float*)d_in[3], Wbf[1], (int)(NW / 8) };
    jobs.j[3] = { (const float*)d_in[5], Wbf[2], (int)(NW / 8) };
    jobs.j[4] = { (const float*)d_in[7], Wbf[3], (int)(NW / 8) };
    jobs.j[5] = { (const float*)d_in[2], bbf[0], (int)(NB / 8) };
    jobs.j[6] = { (const float*)d_in[4], bbf[1], (int)(NB / 8) };
    jobs.j[7] = { (const float*)d_in[6], bbf[2], (int)(NB / 8) };
    jobs.j[8] = { (const float*)d_in[8], bbf[3], (int)(NB / 8) };
    const int total8 = (int)((NX + 4 * NW + 4 * NB) / 8);
    convert_kernel<<<(total8 + 255) / 256, 256, 0, stream>>>(jobs);

    GemmPtrs qkv;
    qkv.W[0] = Wbf[0]; qkv.W[1] = Wbf[1]; qkv.W[2] = Wbf[2];
    qkv.b[0] = bbf[0]; qkv.b[1] = bbf[1]; qkv.b[2] = bbf[2];
    qkv.out[0] = Qw; qkv.out[1] = Kw; qkv.out[2] = Vw;
    dim3 g1((M_TOK + 127) / 128, EMB / 128, 3);
    gemm_bias_nt<<<g1, 256, 0, stream>>>(xbf, qkv, M_TOK, 0);

    // attn writes O over Qw (disjoint per-(b,h) slices; Q consumed into regs
    // before first O store within each block)
    attn_kernel<<<dim3(BSZ * NH), 256, 0, stream>>>(Qw, Kw, Vw, Qw);

    GemmPtrs pr;
    pr.W[0] = pr.W[1] = pr.W[2] = Wbf[3];
    pr.b[0] = pr.b[1] = pr.b[2] = bbf[3];
    pr.out[0] = pr.out[1] = pr.out[2] = d_out;          // fp32 final output
    dim3 g2((M_TOK + 127) / 128, EMB / 128, 1);
    gemm_bias_nt<<<g2, 256, 0, stream>>>(Qw, pr, M_TOK, 1);
}